// Round 8
// baseline (76.857 us; speedup 1.0000x reference)
//
#include <hip/hip_runtime.h>
#include <math.h>

// ---- compile-time physics constants (computed in double, cast to float) ----
constexpr double PI_D         = 3.14159265358979323846;
constexpr double WAVELENGTH_D = 12.398 / 11.3;
constexpr double K_D          = 2.0 * PI_D / WAVELENGTH_D;
constexpr double PIXELSIZE_D  = 5.5e-05 * 2.0;
constexpr double DISTANCE_D   = 0.85;
constexpr double WX_D         = K_D * PIXELSIZE_D / DISTANCE_D / 10.0;   // == WY
constexpr float  INVW2        = (float)(1.0 / (WX_D * WX_D));
constexpr float  TWO_PI_C_L   = (float)(2.0 * PI_D / 4.013 * 2.0);
constexpr float  DEG2RAD      = (float)(PI_D / 180.0);

// oQy is SORTED ascending (donut mask flattened row-major; O_Qy depends only
// on the O-grid row). The y-band |dy - oQy| < QCUT is a contiguous [lo,hi).
//
// Single-dispatch layout: block = one (batch, detector row); 4 waves split the
// row's hit band 4 ways; LDS combine; wave 0 stores ALL outputs directly
// (no memset dispatch, no global atomics).

__global__ __launch_bounds__(256) void img_gen_kernel(
    const float* __restrict__ params,
    const float* __restrict__ dQx,
    const float* __restrict__ dQy,
    const float* __restrict__ dQz,
    const float* __restrict__ oQx,
    const float* __restrict__ oQy,
    const float* __restrict__ oQz,
    float* __restrict__ out,
    int N)
{
    const int blk  = blockIdx.x;          // 0..255 = b*64 + row
    const int b    = blk >> 6;
    const int row  = blk & 63;
    const int lane = threadIdx.x & 63;    // detector column
    const int w    = threadIdx.x >> 6;    // wave id 0..3
    const int pix  = row * 64 + lane;

    const float thickness = params[b * 4 + 0];
    const float strain    = params[b * 4 + 1];
    const float tilt_lr   = params[b * 4 + 2] * DEG2RAD;
    const float tilt_ud   = params[b * 4 + 3] * DEG2RAD;
    const float shift     = TWO_PI_C_L / (1.0f + strain);

    const float dx    = dQx[pix] + shift * tilt_lr;   // per-lane (column-only)
    const float dy    = dQy[pix] + shift * tilt_ud;   // wave-uniform (row-only)
    const float dz    = dQz[pix] - shift;             // per-lane (column-only)
    const float halfT = 0.5f * thickness;

    // |qy| < QCUT  <=>  qy^2*INVW2 < 88  (exp(-88) ~ 6e-39: negligible)
    const float QCUT = sqrtf(88.0f) * (float)WX_D;

    // ---- dual wave-parallel 32-ary lower_bound on sorted oQy ----
    // (each wave computes the identical per-(b,row) result redundantly)
    // lanes 0-31: first n with oQy[n] >= dy-QCUT   -> lo
    // lanes 32-63: first n with oQy[n] >= dy+QCUT  -> hi
    const int   half   = lane >> 5;
    const int   sl     = lane & 31;
    const float target = dy + (half ? QCUT : -QCUT);
    int a = 0, bnd = N;                               // invariant: a <= ans <= bnd
    while (__any(bnd - a > 32)) {
        const int span = bnd - a;
        const int p    = a + (int)(((long long)span * (sl + 1)) / 33); // in [a,bnd)
        const float v  = oQy[min(p, N - 1)];
        const bool pred = (span > 0) && (v < target);
        const unsigned long long m = __ballot(pred);
        const unsigned k = half ? (unsigned)__popcll(m >> 32)
                                : (unsigned)__popcll(m & 0xffffffffull);
        const int anew = (k > 0)  ? a + (int)(((long long)span * k) / 33) + 1 : a;
        const int bnew = (k < 32) ? a + (int)(((long long)span * (k + 1)) / 33) : bnd;
        a = anew; bnd = bnew;
    }
    {   // final: probe all of [a, bnd), width <= 32
        const int  pos   = a + sl;
        const bool valid = pos < bnd;
        const float v    = oQy[min(pos, N - 1)];
        const bool pred  = valid && (v < target);
        const unsigned long long m = __ballot(pred);
        const unsigned k = half ? (unsigned)__popcll(m >> 32)
                                : (unsigned)__popcll(m & 0xffffffffull);
        a += (int)k;
    }
    const int lo = __shfl(a, 0);
    const int hi = __shfl(a, 32);

    // ---- wave w takes the w-th quarter of the band ----
    float acc = 0.0f;
    const int len = hi - lo;
    if (len > 0) {
        const int s = lo + (int)((long long)len * w       / 4);
        const int e = lo + (int)((long long)len * (w + 1) / 4);
        for (int base = s; base < e; base += 64) {
            const int nn = min(base + lane, N - 1);   // coalesced 64-wide load
            const float yv = oQy[nn];
            const float xv = oQx[nn];
            const float zv = oQz[nn];
            const int cnt = min(64, e - base);
            for (int k2 = 0; k2 < cnt; ++k2) {
                const float yb = __shfl(yv, k2);
                const float xb = __shfl(xv, k2);
                const float zb = __shfl(zv, k2);
                const float qy = dy - yb;             // uniform
                const float qx = dx - xb;             // per-lane
                const float qz = dz - zb;             // per-lane
                const float arg   = halfT * qz;       // = pi * (t*qz/pi/2)
                const float sa    = __sinf(arg);
                const float sincv = (arg != 0.0f) ? __fdividef(sa, arg) : 1.0f;
                const float tf    = thickness * sincv * sincv;
                acc += tf * __expf(-(qx * qx + qy * qy) * INVW2);
            }
        }
    }

    // ---- combine the 4 waves in LDS; wave 0 stores (unconditional write) ----
    __shared__ float red[4][64];
    red[w][lane] = acc;
    __syncthreads();
    if (threadIdx.x < 64) {
        const float v = red[0][lane] + red[1][lane] + red[2][lane] + red[3][lane];
        out[b * 4096 + pix] = v;                      // coalesced, every pixel
    }
}

extern "C" void kernel_launch(void* const* d_in, const int* in_sizes, int n_in,
                              void* d_out, int out_size, void* d_ws, size_t ws_size,
                              hipStream_t stream) {
    const float* params = (const float*)d_in[0];
    const float* dQx    = (const float*)d_in[1];
    const float* dQy    = (const float*)d_in[2];
    const float* dQz    = (const float*)d_in[3];
    const float* oQx    = (const float*)d_in[4];
    const float* oQy    = (const float*)d_in[5];
    const float* oQz    = (const float*)d_in[6];
    float*       out    = (float*)d_out;
    const int    N      = in_sizes[4];

    // Single dispatch: every output pixel is written unconditionally, so the
    // 0xAA-poisoned d_out needs no zeroing (memset dispatch deleted).
    img_gen_kernel<<<dim3(256), 256, 0, stream>>>(params, dQx, dQy, dQz,
                                                  oQx, oQy, oQz, out, N);
}

// Round 9
// 74.619 us; speedup vs baseline: 1.0300x; 1.0300x over previous
//
#include <hip/hip_runtime.h>
#include <math.h>

// ---- compile-time physics constants (computed in double, cast to float) ----
constexpr double PI_D         = 3.14159265358979323846;
constexpr double WAVELENGTH_D = 12.398 / 11.3;
constexpr double K_D          = 2.0 * PI_D / WAVELENGTH_D;
constexpr double PIXELSIZE_D  = 5.5e-05 * 2.0;
constexpr double DISTANCE_D   = 0.85;
constexpr double WX_D         = K_D * PIXELSIZE_D / DISTANCE_D / 10.0;   // == WY
constexpr float  INVW2        = (float)(1.0 / (WX_D * WX_D));
constexpr float  TWO_PI_C_L   = (float)(2.0 * PI_D / 4.013 * 2.0);
constexpr float  DEG2RAD      = (float)(PI_D / 180.0);

constexpr int DET    = 4096;   // 64*64 detector pixels
constexpr int NCHUNK = 8;      // contiguous split of each row's hit band

// oQy is SORTED ascending (donut mask flattened row-major; O_Qy depends only
// on the O-grid row). The y-band |dy - oQy| < QCUT is a contiguous [lo,hi).
// Best-measured structure (R7, 72.3 us): 512 blocks (64x8), wave = one
// detector row x one band-eighth; memset + atomicAdd combine.

__global__ __launch_bounds__(256) void img_gen_kernel(
    const float* __restrict__ params,
    const float* __restrict__ dQx,
    const float* __restrict__ dQy,
    const float* __restrict__ dQz,
    const float* __restrict__ oQx,
    const float* __restrict__ oQy,
    const float* __restrict__ oQz,
    float* __restrict__ out,
    int N)
{
    const int tidg = blockIdx.x * 256 + threadIdx.x;  // 0..16383 = b*4096 + pix
    const int b    = tidg >> 12;
    const int pix  = tidg & (DET - 1);
    const int lane = threadIdx.x & 63;                // wave = one detector row
    const int c    = blockIdx.y;                      // band slice index

    const float thickness = params[b * 4 + 0];
    const float strain    = params[b * 4 + 1];
    const float tilt_lr   = params[b * 4 + 2] * DEG2RAD;
    const float tilt_ud   = params[b * 4 + 3] * DEG2RAD;
    const float shift     = TWO_PI_C_L / (1.0f + strain);

    const float dx    = dQx[pix] + shift * tilt_lr;   // per-lane (column)
    const float dy    = dQy[pix] + shift * tilt_ud;   // wave-uniform (row)
    const float dz    = dQz[pix] - shift;             // per-lane (column)
    const float halfT = 0.5f * thickness;

    // |qy| < QCUT  <=>  gy = qy^2*INVW2 < 88  (exp(-88) ~ 6e-39: negligible)
    const float QCUT = sqrtf(88.0f) * (float)WX_D;

    // ---- dual wave-parallel 32-ary lower_bound on sorted oQy ----
    // lanes 0-31: first n with oQy[n] >= dy-QCUT   -> lo
    // lanes 32-63: first n with oQy[n] >= dy+QCUT  -> hi
    const int   half   = lane >> 5;
    const int   sl     = lane & 31;
    const float target = dy + (half ? QCUT : -QCUT);
    int a = 0, bnd = N;                               // invariant: a <= ans <= bnd
    while (__any(bnd - a > 32)) {
        const int span = bnd - a;
        const int p    = a + (int)(((long long)span * (sl + 1)) / 33); // in [a,bnd)
        const float v  = oQy[min(p, N - 1)];
        const bool pred = (span > 0) && (v < target);
        const unsigned long long m = __ballot(pred);
        const unsigned k = half ? (unsigned)__popcll(m >> 32)
                                : (unsigned)__popcll(m & 0xffffffffull);
        const int anew = (k > 0)  ? a + (int)(((long long)span * k) / 33) + 1 : a;
        const int bnew = (k < 32) ? a + (int)(((long long)span * (k + 1)) / 33) : bnd;
        a = anew; bnd = bnew;
    }
    {   // final: probe all of [a, bnd), width <= 32
        const int  pos   = a + sl;
        const bool valid = pos < bnd;
        const float v    = oQy[min(pos, N - 1)];
        const bool pred  = valid && (v < target);
        const unsigned long long m = __ballot(pred);
        const unsigned k = half ? (unsigned)__popcll(m >> 32)
                                : (unsigned)__popcll(m & 0xffffffffull);
        a += (int)k;
    }
    const int lo = __shfl(a, 0);
    const int hi = __shfl(a, 32);

    // ---- equal contiguous slice of the band for this chunk ----
    float acc = 0.0f;
    const int len = hi - lo;
    if (len > 0) {
        const int s = lo + (int)((long long)len * c       / NCHUNK);
        const int e = lo + (int)((long long)len * (c + 1) / NCHUNK);
        for (int base = s; base < e; base += 64) {
            const int nn = min(base + lane, N - 1);   // coalesced 64-wide load
            const float yv = oQy[nn];
            const float xv = oQx[nn];
            const float zv = oQz[nn];
            const int cnt = min(64, e - base);
            for (int k2 = 0; k2 < cnt; ++k2) {
                const float yb = __shfl(yv, k2);
                const float xb = __shfl(xv, k2);
                const float zb = __shfl(zv, k2);
                const float qy = dy - yb;             // uniform
                const float qx = dx - xb;             // per-lane
                const float qz = dz - zb;             // per-lane
                const float arg   = halfT * qz;       // = pi * (t*qz/pi/2)
                const float sa    = __sinf(arg);
                const float sincv = (arg != 0.0f) ? __fdividef(sa, arg) : 1.0f;
                const float tf    = thickness * sincv * sincv;
                acc += tf * __expf(-(qx * qx + qy * qy) * INVW2);
            }
        }
    }
    if (acc != 0.0f) atomicAdd(&out[tidg], acc);
}

extern "C" void kernel_launch(void* const* d_in, const int* in_sizes, int n_in,
                              void* d_out, int out_size, void* d_ws, size_t ws_size,
                              hipStream_t stream) {
    const float* params = (const float*)d_in[0];
    const float* dQx    = (const float*)d_in[1];
    const float* dQy    = (const float*)d_in[2];
    const float* dQz    = (const float*)d_in[3];
    const float* oQx    = (const float*)d_in[4];
    const float* oQy    = (const float*)d_in[5];
    const float* oQz    = (const float*)d_in[6];
    float*       out    = (float*)d_out;
    const int    N      = in_sizes[4];

    // d_out is re-poisoned to 0xAA before every timed launch; zero it first.
    hipMemsetAsync(d_out, 0, (size_t)out_size * sizeof(float), stream);

    dim3 grid((4 * DET) / 256, NCHUNK);   // 64 x 8 blocks, 256 thr
    img_gen_kernel<<<grid, 256, 0, stream>>>(params, dQx, dQy, dQz,
                                             oQx, oQy, oQz, out, N);
}